// Round 1
// baseline (18.190 us; speedup 1.0000x reference)
//
#include <hip/hip_runtime.h>
#include <math.h>

#define M_CH 3
#define DIL 4
#define EPS_ 1e-8f
#define L_ 32
#define Q_ 4096

__global__ __launch_bounds__(256) void feature_kernel(
    const float* __restrict__ x,       // (B, C, Q)
    const float* __restrict__ shp,     // (L,)
    const float* __restrict__ posMap,  // (W,)
    const float* __restrict__ posSlope_p, // scalar
    float* __restrict__ out,           // (B,)
    int C, int W)
{
    __shared__ float sx[Q_];
    __shared__ float ssh[L_];
    __shared__ float smin[4];

    const int b   = blockIdx.x;
    const int tid = threadIdx.x;
    const float* __restrict__ xr = x + ((size_t)b * C + M_CH) * Q_;

    // stage the channel-3 row into LDS, vectorized float4 (16 B/lane)
    const float4* xr4 = reinterpret_cast<const float4*>(xr);
    float4* sx4 = reinterpret_cast<float4*>(sx);
    #pragma unroll
    for (int i = 0; i < Q_ / 4 / 256; ++i)
        sx4[tid + i * 256] = xr4[tid + i * 256];
    if (tid < L_) ssh[tid] = shp[tid];
    __syncthreads();

    const float posSlope = posSlope_p[0];

    // shapelet into registers + its constants (uniform across lanes)
    float s_reg[L_];
    float Ssum = 0.f, S2 = 0.f;
    #pragma unroll
    for (int j = 0; j < L_; ++j) {
        s_reg[j] = ssh[j];
        Ssum += s_reg[j];
        S2   += s_reg[j] * s_reg[j];
    }

    const float invL = 1.0f / (float)L_;
    float best = INFINITY;

    for (int w = tid; w < W; w += 256) {
        float sum = 0.f, sq = 0.f, sxs = 0.f;
        #pragma unroll
        for (int j = 0; j < L_; ++j) {
            float v = sx[w + j * DIL];
            sum += v;
            sq  = fmaf(v, v, sq);
            sxs = fmaf(s_reg[j], v, sxs);
        }
        float m   = sum * invL;
        float var = (sq - (float)L_ * m * m) * (1.0f / (float)(L_ - 1));
        var = fmaxf(var, 0.0f);
        float sd  = sqrtf(var) + EPS_;
        float inv = 1.0f / sd;
        // d = S2/L - 2*(sxs - m*Ssum)/(L*sd) + (sq/L - m*m)/sd^2
        float d = S2 * invL
                - 2.0f * (sxs - m * Ssum) * invL * inv
                + (sq * invL - m * m) * inv * inv;

        float z   = -posMap[w];
        float elu = (z > 0.f) ? z : (expf(z) - 1.0f);
        float wv  = fmaf(posSlope, elu, 2.0f);
        best = fminf(best, d * wv);
    }

    // wave (64-lane) min reduction
    #pragma unroll
    for (int off = 32; off > 0; off >>= 1)
        best = fminf(best, __shfl_down(best, off, 64));
    if ((tid & 63) == 0) smin[tid >> 6] = best;
    __syncthreads();
    if (tid == 0) {
        float r = fminf(fminf(smin[0], smin[1]), fminf(smin[2], smin[3]));
        out[b] = fmaxf(r, 0.0f);
    }
}

extern "C" void kernel_launch(void* const* d_in, const int* in_sizes, int n_in,
                              void* d_out, int out_size, void* d_ws, size_t ws_size,
                              hipStream_t stream) {
    const float* x        = (const float*)d_in[0];
    const float* shp      = (const float*)d_in[1];
    const float* posMap   = (const float*)d_in[2];
    const float* posSlope = (const float*)d_in[3];
    float* out = (float*)d_out;

    const int L = in_sizes[1];          // 32
    const int W = in_sizes[2];          // 3972
    const int Q = W + (L - 1) * DIL;    // 4096
    const int C = 8;
    const int B = in_sizes[0] / (C * Q); // 512

    feature_kernel<<<B, 256, 0, stream>>>(x, shp, posMap, posSlope, out, C, W);
}

// Round 2
// 11.565 us; speedup vs baseline: 1.5729x; 1.5729x over previous
//
#include <hip/hip_runtime.h>
#include <math.h>

#define M_CH 3
#define DILC 4
#define EPSC 1e-8f
#define LC   32
#define QC   4096
#define WC   3972   // QC - (LC-1)*DILC
#define NWC  993    // WC / DILC  (windows per residue class)
#define RUNC 16     // ceil(NWC / 64) windows per lane

// Skewed LDS index: +1 float pad per 64 floats -> lane-stride 64 becomes
// bank-stride 1 (conflict-free for the sliding-window access pattern).
__device__ __forceinline__ int skew(int a) { return a + (a >> 6); }

__global__ __launch_bounds__(256) void feature_kernel(
    const float* __restrict__ x,          // (B, C, Q)
    const float* __restrict__ shp,        // (L,)
    const float* __restrict__ posMap,     // (W,)
    const float* __restrict__ posSlope_p, // scalar
    float* __restrict__ out,              // (B,)
    int C)
{
    __shared__ float sx[4352];   // skewed x row   (max idx 4284)
    __shared__ float sw[4160];   // skewed posweight (max idx 4158)
    __shared__ float smin[4];

    const int tid = threadIdx.x;
    const int b   = blockIdx.x;
    const float* __restrict__ xr = x + ((size_t)b * C + M_CH) * QC;

    // ---- stage x row into skewed LDS (float4 global loads) ----
    {
        const float4* xr4 = reinterpret_cast<const float4*>(xr);
        #pragma unroll
        for (int i = 0; i < QC / 4 / 256; ++i) {
            int a4 = tid + i * 256;
            float4 v = xr4[a4];
            int s = skew(a4 * 4);           // float4 stays within a 64-group
            sx[s] = v.x; sx[s + 1] = v.y; sx[s + 2] = v.z; sx[s + 3] = v.w;
        }
    }
    // ---- stage position weights w(pos) = posSlope*elu(-posMap)+2 (skewed) ----
    {
        const float ps = posSlope_p[0];
        const float4* pm4 = reinterpret_cast<const float4*>(posMap);
        #pragma unroll
        for (int i = 0; i < 4; ++i) {
            int a4 = tid + i * 256;
            if (a4 < NWC) {                  // WC/4 == NWC float4 chunks
                float4 z = pm4[a4];
                float e0 = (-z.x > 0.f) ? -z.x : (__expf(-z.x) - 1.f);
                float e1 = (-z.y > 0.f) ? -z.y : (__expf(-z.y) - 1.f);
                float e2 = (-z.z > 0.f) ? -z.z : (__expf(-z.z) - 1.f);
                float e3 = (-z.w > 0.f) ? -z.w : (__expf(-z.w) - 1.f);
                int s = skew(a4 * 4);
                sw[s]     = fmaf(ps, e0, 2.0f);
                sw[s + 1] = fmaf(ps, e1, 2.0f);
                sw[s + 2] = fmaf(ps, e2, 2.0f);
                sw[s + 3] = fmaf(ps, e3, 2.0f);
            }
        }
    }
    __syncthreads();

    // shapelet: uniform address -> scalar loads/SGPRs
    float sreg[LC];
    #pragma unroll
    for (int j = 0; j < LC; ++j) sreg[j] = shp[j];
    float Ssum = 0.f, S2 = 0.f;
    #pragma unroll
    for (int j = 0; j < LC; ++j) { Ssum += sreg[j]; S2 = fmaf(sreg[j], sreg[j], S2); }

    const int lane = tid & 63;
    const int r    = tid >> 6;        // residue class 0..3 (one per wave)
    const int w0   = 64 * lane + r;   // first window of this lane's run

    // ---- fill rotating register buffer: buf[p] = x[w0 + 4p] ----
    float buf[32];
    #pragma unroll
    for (int p = 0; p < 32; ++p) {
        int a = w0 + DILC * p;
        buf[p] = sx[skew(a)];
    }
    float sum = 0.f, sq = 0.f;
    #pragma unroll
    for (int p = 0; p < 32; ++p) { sum += buf[p]; sq = fmaf(buf[p], buf[p], sq); }

    const float invL  = 1.0f / 32.0f;
    const float invL1 = 1.0f / 31.0f;
    float best = INFINITY;

    #pragma unroll
    for (int k = 0; k < RUNC; ++k) {
        if (k > 0) {
            // slide: drop x[w0+4(k-1)], add x[w0+4k+124]; same rotating slot
            int slot = (k + 31) & 31;
            float oldv = buf[slot];
            int a = w0 + DILC * k + (LC - 1) * DILC;
            float newv = sx[skew(a)];
            sum += newv - oldv;
            sq  += fmaf(newv, newv, -(oldv * oldv));
            buf[slot] = newv;
        }
        float dot = 0.f;
        #pragma unroll
        for (int j = 0; j < LC; ++j)
            dot = fmaf(sreg[j], buf[(k + j) & 31], dot);

        const bool valid = (RUNC * lane + k) < NWC;
        const int  w     = w0 + DILC * k;
        float wv = sw[skew(w)];

        float m   = sum * invL;
        float var = (sq - 32.0f * m * m) * invL1;
        var = fmaxf(var, 0.0f);
        float sd  = __builtin_amdgcn_sqrtf(var) + EPSC;
        float inv = __builtin_amdgcn_rcpf(sd);
        // d = S2/L - 2*(dot - m*Ssum)/(L*sd) + (sq/L - m^2)/sd^2
        float d = S2 * invL
                - 2.0f * (dot - m * Ssum) * invL * inv
                + (sq * invL - m * m) * inv * inv;

        float f = valid ? d * wv : INFINITY;
        best = fminf(best, f);
    }

    // ---- block min reduction ----
    #pragma unroll
    for (int off = 32; off > 0; off >>= 1)
        best = fminf(best, __shfl_down(best, off, 64));
    if (lane == 0) smin[r] = best;
    __syncthreads();
    if (tid == 0) {
        float m01 = fminf(smin[0], smin[1]);
        float m23 = fminf(smin[2], smin[3]);
        out[b] = fmaxf(fminf(m01, m23), 0.0f);
    }
}

extern "C" void kernel_launch(void* const* d_in, const int* in_sizes, int n_in,
                              void* d_out, int out_size, void* d_ws, size_t ws_size,
                              hipStream_t stream) {
    const float* x        = (const float*)d_in[0];
    const float* shp      = (const float*)d_in[1];
    const float* posSlope = (const float*)d_in[3];
    const float* posMap   = (const float*)d_in[2];
    float* out = (float*)d_out;

    const int C = 8;
    const int B = in_sizes[0] / (C * QC);   // 512

    feature_kernel<<<B, 256, 0, stream>>>(x, shp, posMap, posSlope, out, C);
}